// Round 6
// baseline (319.028 us; speedup 1.0000x reference)
//
#include <hip/hip_runtime.h>
#include <stdint.h>

// GeoAwarePooling B=4, N=40000, C=128, V=4.
// xyz is broadcast across views -> per-point MLP runs once over B*N points.
// v6: occupancy-first. K=16 MFMA chain (GEMM C/D layout == next GEMM B layout,
// zero transpose). All per-lane constants in LDS; bit_cast instead of unions;
// __launch_bounds__(256,4); 1280-block balanced grid; coalesced VALU pool.

#define NPTS 40000
#define CD   128

typedef __attribute__((ext_vector_type(4))) short bf4_t;
typedef __attribute__((ext_vector_type(8))) short bf8_t;
typedef __attribute__((ext_vector_type(4))) float f4_t;

__device__ __forceinline__ unsigned short f2bfu(float f){
  unsigned u = __float_as_uint(f);
  u += 0x7FFFu + ((u>>16)&1u);               // RNE
  return (unsigned short)(u>>16);
}
__device__ __forceinline__ float bfhi_f(float f){   // f rounded to bf16, as f32
  return __uint_as_float(((unsigned)f2bfu(f))<<16);
}
__device__ __forceinline__ unsigned pk2(float a, float b){
  return (unsigned)f2bfu(a) | ((unsigned)f2bfu(b)<<16);
}
__device__ __forceinline__ unsigned pkt(float a, float b){  // truncating pack
  return (__float_as_uint(a)>>16) | (__float_as_uint(b) & 0xFFFF0000u);
}
__device__ __forceinline__ float uplo(unsigned u){ return __uint_as_float(u<<16); }
__device__ __forceinline__ float uphi(unsigned u){ return __uint_as_float(u & 0xFFFF0000u); }
__device__ __forceinline__ unsigned fenc(float f){  // order-preserving key
  unsigned u = __float_as_uint(f);
  return (u & 0x80000000u) ? ~u : (u | 0x80000000u);
}
__device__ __forceinline__ float fdec(unsigned k){
  return (k & 0x80000000u) ? __uint_as_float(k & 0x7FFFFFFFu) : __uint_as_float(~k);
}
__device__ __forceinline__ bf4_t u2bf(uint2 v){ return __builtin_bit_cast(bf4_t, v); }
__device__ __forceinline__ bf4_t uu2bf(unsigned x, unsigned y){
  uint2 v; v.x = x; v.y = y; return __builtin_bit_cast(bf4_t, v);
}

#if __has_builtin(__builtin_amdgcn_mfma_f32_16x16x16bf16_1k)
__device__ __forceinline__ f4_t mfma16(bf4_t a, bf4_t b, f4_t c){
  return __builtin_amdgcn_mfma_f32_16x16x16bf16_1k(a, b, c, 0, 0, 0);
}
#else
// emulate K=16 with zero-padded K=32: logical slot 4g+r -> physical 8g+r on
// BOTH operands, so the dot product is identical. Register-level concat.
__device__ __forceinline__ f4_t mfma16(bf4_t a, bf4_t b, f4_t c){
  const bf4_t z = {0,0,0,0};
  bf8_t A = __builtin_shufflevector(a, z, 0,1,2,3,4,5,6,7);
  bf8_t B = __builtin_shufflevector(b, z, 0,1,2,3,4,5,6,7);
  return __builtin_amdgcn_mfma_f32_16x16x32_bf16(A, B, c, 0, 0, 0);
}
#endif

__global__ __launch_bounds__(256)
void k_init(unsigned* __restrict__ kmax, unsigned* __restrict__ kmin,
            float* __restrict__ denom, float* __restrict__ pool_acc){
  int t = blockIdx.x*256 + threadIdx.x;
  if (t < 512){ kmax[t] = 0u; kmin[t] = 0xFFFFFFFFu; }
  if (t < 16) denom[t] = 0.f;
  if (t < 2048) pool_acc[t] = 0.f;
}

// ---------------------------------------------------------------------------
// Phase A: y=xyz@W1+b1 (K=16 MFMA, hi/lo split, fp32-exact); h=relu(LN1(y));
// z2=(h@W2+b2, normalized pre-affine) -> global, lane-chunk coalesced layout.
// Per-channel max/min tracked packed-bf16 in regs. 2 same-batch tiles/wave.
// Grid: 1280 blocks (320/batch), 4 waves.
// ---------------------------------------------------------------------------
__global__ __launch_bounds__(256, 4)
void k_A(const float* __restrict__ xyz,
         const float* __restrict__ W1, const float* __restrict__ b1,
         const float* __restrict__ g1, const float* __restrict__ be1,
         const float* __restrict__ W2, const float* __restrict__ b2,
         unsigned* __restrict__ z2u,
         unsigned* __restrict__ kmax, unsigned* __restrict__ kmin)
{
  __shared__ uint2 W2Fu[4096];   // 32 KiB: per-lane K=16 A-frags of W2^T
  __shared__ uint2 A1L[512];     // 4 KiB: GEMM1 A-frags [mt*64+lane]
  __shared__ uint2 P1u[32], P2u[32], P3u[32];  // g1, be1, b2 packed pairs

  const int tid = threadIdx.x;
  for (int idx = tid; idx < 4096; idx += 256){
    int fid = idx >> 6, l = idx & 63;
    int mti = fid >> 3, mto = fid & 7;
    int lm = l & 15, lg = l >> 4;
    int ci0 = 16*mti + 4*lg, co = 16*mto + lm;
    uint2 v;
    v.x = pk2(W2[(ci0+0)*CD+co], W2[(ci0+1)*CD+co]);
    v.y = pk2(W2[(ci0+2)*CD+co], W2[(ci0+3)*CD+co]);
    W2Fu[idx] = v;
  }
  for (int e = tid; e < 512; e += 256){
    int mt = e >> 6, l = e & 63;
    int lm = l & 15, lg = l >> 4;
    int c = 16*mt + lm;
    float w0=W1[c], w1=W1[CD+c], w2=W1[2*CD+c], bb=b1[c];
    uint2 v; v.x=0u; v.y=0u;
    if (lg==0){ v.x = pk2(w0,w1); v.y = pk2(w2,w0); }
    else if (lg==1){ v.x = pk2(w1,w2); v.y = pk2(w0-bfhi_f(w0), w1-bfhi_f(w1)); }
    else if (lg==2){ v.x = pk2(w2-bfhi_f(w2), bb); v.y = pk2(bb-bfhi_f(bb), 0.f); }
    A1L[e] = v;
  }
  if (tid < 32){
    int t4 = tid*4;
    uint2 v;
    v.x = pk2(g1[t4], g1[t4+1]);  v.y = pk2(g1[t4+2], g1[t4+3]);  P1u[tid] = v;
    v.x = pk2(be1[t4],be1[t4+1]); v.y = pk2(be1[t4+2],be1[t4+3]); P2u[tid] = v;
    v.x = pk2(b2[t4], b2[t4+1]);  v.y = pk2(b2[t4+2], b2[t4+3]);  P3u[tid] = v;
  }
  __syncthreads();

  const int wave = tid>>6, lane = tid&63;
  const int m = lane&15, g = lane>>4;
  const int b  = blockIdx.x / 320;
  const int wb = (blockIdx.x % 320)*4 + wave;    // 0..1279 within batch
  const float* xyzb = xyz + (size_t)(3*b)*NPTS;

  unsigned zmx[16], zmn[16];
  const unsigned NEG = pkt(-1e30f,-1e30f), POS = pkt(1e30f,1e30f);
#pragma unroll
  for (int j=0;j<16;++j){ zmx[j]=NEG; zmn[j]=POS; }

#pragma unroll 1
  for (int rep = 0; rep < 2; ++rep){
    const int tb = wb + rep*1280;
    if (tb >= 2500) break;
    const int it = b*2500 + tb;            // global tile id
    const int n = tb*16 + m;
    float px = xyzb[n], py = xyzb[NPTS+n], pz = xyzb[2*NPTS+n];

    uint2 B1u; B1u.x = 0u; B1u.y = 0u;
    if (g==0){ B1u.x = pk2(px,py); B1u.y = pk2(pz, px-bfhi_f(px)); }
    else if (g==1){ B1u.x = pk2(py-bfhi_f(py), pz-bfhi_f(pz)); B1u.y = pk2(px,py); }
    else if (g==2){ B1u.x = pk2(pz, 1.0f); B1u.y = pk2(1.0f, 0.f); }
    bf4_t B1 = u2bf(B1u);

    f4_t acc[8];
#pragma unroll
    for (int mt=0;mt<8;++mt)
      acc[mt] = mfma16(u2bf(A1L[mt*64+lane]), B1, (f4_t){0.f,0.f,0.f,0.f});

    // LN1
    float s1=0.f, s2=0.f;
#pragma unroll
    for (int mt=0;mt<8;++mt)
#pragma unroll
      for (int r=0;r<4;++r){ float v=acc[mt][r]; s1+=v; s2=fmaf(v,v,s2); }
    s1 += __shfl_xor(s1,16); s1 += __shfl_xor(s1,32);
    s2 += __shfl_xor(s2,16); s2 += __shfl_xor(s2,32);
    float mu = s1*(1.f/128.f);
    float rs = rsqrtf(fmaxf(s2*(1.f/128.f)-mu*mu,0.f)+1e-5f);

    // affine+relu -> packed h (this IS GEMM2's B-fragment, no movement)
    unsigned hu[16];
#pragma unroll
    for (int mt=0;mt<8;++mt){
      uint2 gv = P1u[4*mt+g], bv = P2u[4*mt+g];
      float h0 = fmaxf(0.f, fmaf((acc[mt][0]-mu)*rs, uplo(gv.x), uplo(bv.x)));
      float h1 = fmaxf(0.f, fmaf((acc[mt][1]-mu)*rs, uphi(gv.x), uphi(bv.x)));
      float h2 = fmaxf(0.f, fmaf((acc[mt][2]-mu)*rs, uplo(gv.y), uplo(bv.y)));
      float h3 = fmaxf(0.f, fmaf((acc[mt][3]-mu)*rs, uphi(gv.y), uphi(bv.y)));
      hu[2*mt]   = pk2(h0,h1);
      hu[2*mt+1] = pk2(h2,h3);
    }

    // GEMM2: 64 K=16 MFMAs, A from LDS
    f4_t a2[8];
#pragma unroll
    for (int mt=0;mt<8;++mt) a2[mt]=(f4_t){0.f,0.f,0.f,0.f};
#pragma unroll
    for (int mti=0;mti<8;++mti){
      bf4_t Bf = uu2bf(hu[2*mti], hu[2*mti+1]);
#pragma unroll
      for (int mto=0;mto<8;++mto)
        a2[mto] = mfma16(u2bf(W2Fu[(mti*8+mto)*64 + lane]), Bf, a2[mto]);
    }

    // +b2, LN2 -> z (pre-affine)
    s1=0.f; s2=0.f;
#pragma unroll
    for (int mt=0;mt<8;++mt){
      uint2 bv = P3u[4*mt+g];
      a2[mt][0]+=uplo(bv.x); a2[mt][1]+=uphi(bv.x);
      a2[mt][2]+=uplo(bv.y); a2[mt][3]+=uphi(bv.y);
#pragma unroll
      for (int r=0;r<4;++r){ float v=a2[mt][r]; s1+=v; s2=fmaf(v,v,s2); }
    }
    s1 += __shfl_xor(s1,16); s1 += __shfl_xor(s1,32);
    s2 += __shfl_xor(s2,16); s2 += __shfl_xor(s2,32);
    mu = s1*(1.f/128.f);
    rs = rsqrtf(fmaxf(s2*(1.f/128.f)-mu*mu,0.f)+1e-5f);

    unsigned zu[16];
#pragma unroll
    for (int mt=0;mt<8;++mt){
      float z0=(a2[mt][0]-mu)*rs, z1=(a2[mt][1]-mu)*rs;
      float z2v=(a2[mt][2]-mu)*rs, z3=(a2[mt][3]-mu)*rs;
      zu[2*mt]   = pk2(z0,z1);
      zu[2*mt+1] = pk2(z2v,z3);
      zmx[2*mt]   = pkt(fmaxf(uplo(zmx[2*mt]),  z0), fmaxf(uphi(zmx[2*mt]),  z1));
      zmx[2*mt+1] = pkt(fmaxf(uplo(zmx[2*mt+1]),z2v), fmaxf(uphi(zmx[2*mt+1]),z3));
      zmn[2*mt]   = pkt(fminf(uplo(zmn[2*mt]),  z0), fminf(uphi(zmn[2*mt]),  z1));
      zmn[2*mt+1] = pkt(fminf(uplo(zmn[2*mt+1]),z2v), fminf(uphi(zmn[2*mt+1]),z3));
    }

    // coalesced store: 4 x dwordx4, 1 KB contiguous per inst
    size_t base = (size_t)it*1024 + lane*4;
#pragma unroll
    for (int s=0;s<4;++s){
      uint4 v; v.x=zu[4*s]; v.y=zu[4*s+1]; v.z=zu[4*s+2]; v.w=zu[4*s+3];
      *reinterpret_cast<uint4*>(&z2u[base + s*256]) = v;
    }
  }

  // reduce extremes across m, one atomic set per (g,channel)
#pragma unroll
  for (int j=0;j<16;++j){
    float xlo = uplo(zmx[j]), xhi = uphi(zmx[j]);
    float nlo = uplo(zmn[j]), nhi = uphi(zmn[j]);
#pragma unroll
    for (int o=1;o<16;o<<=1){
      xlo = fmaxf(xlo, __shfl_xor(xlo,o)); xhi = fmaxf(xhi, __shfl_xor(xhi,o));
      nlo = fminf(nlo, __shfl_xor(nlo,o)); nhi = fminf(nhi, __shfl_xor(nhi,o));
    }
    if (m==0){
      int mt=j>>1, h=j&1; int c = 16*mt + 4*g + 2*h;
      atomicMax(&kmax[b*CD+c],   fenc(xlo));
      atomicMax(&kmax[b*CD+c+1], fenc(xhi));
      atomicMin(&kmin[b*CD+c],   fenc(nlo));
      atomicMin(&kmin[b*CD+c+1], fenc(nhi));
    }
  }
}

// global[b][c] = g2*(g2>=0?zmax:zmin)+be2 ; gcomb = b3 + be2@W3top + global@W3bot
__global__ __launch_bounds__(256)
void k_global(const unsigned* __restrict__ kmax, const unsigned* __restrict__ kmin,
              const float* __restrict__ g2, const float* __restrict__ be2,
              const float* __restrict__ W3, const float* __restrict__ b3,
              float* __restrict__ globalv, float* __restrict__ gcomb)
{
  __shared__ float gs[128], bs[128], part[256];
  int b = blockIdx.x;
  int t = threadIdx.x;
  if (t < 128){
    float gg = g2[t];
    float zx = fdec(kmax[b*CD+t]), zn = fdec(kmin[b*CD+t]);
    float gl = (gg>=0.f ? gg*zx : gg*zn) + be2[t];
    gs[t] = gl;
    globalv[b*CD+t] = gl;
    bs[t] = be2[t];
  }
  __syncthreads();
  int c = t & 127, half = t >> 7;
  float accv = 0.f;
  if (half==0){
    for (int k=0;k<128;++k) accv = fmaf(bs[k], W3[k*CD+c], accv);
    accv += b3[c];
  } else {
    for (int k=0;k<128;++k) accv = fmaf(gs[k], W3[(128+k)*CD+c], accv);
  }
  part[t] = accv;
  __syncthreads();
  if (half==0) gcomb[b*CD+c] = part[c] + part[128+c];
}

// ---------------------------------------------------------------------------
// Phase B: u = z2@(g2*W3top) + gcomb; h2=relu(LN3(u)); w=2*sigmoid(h2@W4)
// z2 reloaded coalesced into exact register state; same K=16 chain.
// ---------------------------------------------------------------------------
__global__ __launch_bounds__(256, 4)
void k_B(const unsigned* __restrict__ z2u, const float* __restrict__ g2,
         const float* __restrict__ W3, const float* __restrict__ g3,
         const float* __restrict__ be3, const float* __restrict__ W4,
         const float* __restrict__ masks, const float* __restrict__ gcomb,
         unsigned short* __restrict__ mwT, float* __restrict__ denom)
{
  __shared__ uint2 W3Fu[4096];   // g2 folded into W3top rows
  __shared__ uint2 Pg[32], Pb[32], Pw[32];   // g3, be3, W4 packed pairs

  const int tid = threadIdx.x;
  for (int idx = tid; idx < 4096; idx += 256){
    int fid = idx >> 6, l = idx & 63;
    int mti = fid >> 3, mto = fid & 7;
    int lm = l & 15, lg = l >> 4;
    int ci0 = 16*mti + 4*lg, co = 16*mto + lm;
    uint2 v;
    v.x = pk2(g2[ci0+0]*W3[(ci0+0)*CD+co], g2[ci0+1]*W3[(ci0+1)*CD+co]);
    v.y = pk2(g2[ci0+2]*W3[(ci0+2)*CD+co], g2[ci0+3]*W3[(ci0+3)*CD+co]);
    W3Fu[idx] = v;
  }
  if (tid < 32){
    int t4 = tid*4;
    uint2 v;
    v.x = pk2(g3[t4], g3[t4+1]);  v.y = pk2(g3[t4+2], g3[t4+3]);  Pg[tid] = v;
    v.x = pk2(be3[t4],be3[t4+1]); v.y = pk2(be3[t4+2],be3[t4+3]); Pb[tid] = v;
    v.x = pk2(W4[t4], W4[t4+1]);  v.y = pk2(W4[t4+2], W4[t4+3]);  Pw[tid] = v;
  }
  __syncthreads();

  const int wave = tid>>6, lane = tid&63;
  const int m = lane&15, g = lane>>4;
  const int b  = blockIdx.x / 320;
  const int wb = (blockIdx.x % 320)*4 + wave;

  float gcv[32];
#pragma unroll
  for (int i=0;i<32;++i){
    int c = 16*(i>>2) + 4*g + (i&3);
    gcv[i] = gcomb[b*CD + c];
  }

  float dacc = 0.f;

#pragma unroll 1
  for (int rep = 0; rep < 2; ++rep){
    const int tb = wb + rep*1280;
    if (tb >= 2500) break;
    const int it = b*2500 + tb;
    const int n = tb*16 + m;

    unsigned zu[16];
    size_t base = (size_t)it*1024 + lane*4;
#pragma unroll
    for (int s=0;s<4;++s){
      uint4 v = *reinterpret_cast<const uint4*>(&z2u[base + s*256]);
      zu[4*s]=v.x; zu[4*s+1]=v.y; zu[4*s+2]=v.z; zu[4*s+3]=v.w;
    }

    f4_t a3[8];
#pragma unroll
    for (int mt=0;mt<8;++mt) a3[mt]=(f4_t){0.f,0.f,0.f,0.f};
#pragma unroll
    for (int mti=0;mti<8;++mti){
      bf4_t Bf = uu2bf(zu[2*mti], zu[2*mti+1]);
#pragma unroll
      for (int mto=0;mto<8;++mto)
        a3[mto] = mfma16(u2bf(W3Fu[(mti*8+mto)*64 + lane]), Bf, a3[mto]);
    }

    float s1=0.f, s2=0.f;
#pragma unroll
    for (int mt=0;mt<8;++mt)
#pragma unroll
      for (int r=0;r<4;++r){
        float v = a3[mt][r] + gcv[4*mt+r]; a3[mt][r]=v; s1+=v; s2=fmaf(v,v,s2);
      }
    s1 += __shfl_xor(s1,16); s1 += __shfl_xor(s1,32);
    s2 += __shfl_xor(s2,16); s2 += __shfl_xor(s2,32);
    float mu = s1*(1.f/128.f);
    float rs = rsqrtf(fmaxf(s2*(1.f/128.f)-mu*mu,0.f)+1e-5f);

    float U = 0.f;
#pragma unroll
    for (int mt=0;mt<8;++mt){
      uint2 gv = Pg[4*mt+g], bv = Pb[4*mt+g], wv = Pw[4*mt+g];
      float h0 = fmaxf(0.f, fmaf((a3[mt][0]-mu)*rs, uplo(gv.x), uplo(bv.x)));
      float h1 = fmaxf(0.f, fmaf((a3[mt][1]-mu)*rs, uphi(gv.x), uphi(bv.x)));
      float h2 = fmaxf(0.f, fmaf((a3[mt][2]-mu)*rs, uplo(gv.y), uplo(bv.y)));
      float h3 = fmaxf(0.f, fmaf((a3[mt][3]-mu)*rs, uphi(gv.y), uphi(bv.y)));
      U = fmaf(h0, uplo(wv.x), U); U = fmaf(h1, uphi(wv.x), U);
      U = fmaf(h2, uplo(wv.y), U); U = fmaf(h3, uphi(wv.y), U);
    }
    U += __shfl_xor(U,16); U += __shfl_xor(U,32);
    float w = 2.f/(1.f + __expf(-U));
    float msk = masks[(size_t)(4*b+g)*NPTS + n];
    mwT[(size_t)(b*4+g)*NPTS + n] = f2bfu(msk*w);
    dacc += msk*w;
  }

  dacc += __shfl_xor(dacc,1); dacc += __shfl_xor(dacc,2);
  dacc += __shfl_xor(dacc,4); dacc += __shfl_xor(dacc,8);
  if (m==0) atomicAdd(&denom[b*4+g], dacc);
}

// pooled[b,v,c] = sum_n mw[b,v,n]*feat[b,c,n]  — coalesced VALU reduction.
// block = (b, c-group of 16, n-chunk of 2500); 256 thr = 16 c-rows x 16 lanes.
__global__ __launch_bounds__(256)
void k_pool(const float* __restrict__ feat, const unsigned short* __restrict__ mwT,
            float* __restrict__ pool_acc)
{
  const int b   = blockIdx.x >> 7;
  const int cg  = (blockIdx.x >> 4) & 7;
  const int nch = blockIdx.x & 15;
  const int cl  = threadIdx.x >> 4, ln = threadIdx.x & 15;
  const int c   = cg*16 + cl;
  const int ns  = nch*2500;
  const float* f = &feat[((size_t)b*CD + c)*NPTS];
  const unsigned short* mw = &mwT[(size_t)b*4*NPTS];
  float a0=0.f, a1=0.f, a2=0.f, a3=0.f;
#pragma unroll 2
  for (int itr=0; itr<40; ++itr){
    int n = ns + itr*64 + ln*4;
    if (n < ns + 2500){
      float4 fv = *reinterpret_cast<const float4*>(&f[n]);
      uint2 m0 = *reinterpret_cast<const uint2*>(&mw[0*NPTS+n]);
      uint2 m1 = *reinterpret_cast<const uint2*>(&mw[1*NPTS+n]);
      uint2 m2 = *reinterpret_cast<const uint2*>(&mw[2*NPTS+n]);
      uint2 m3 = *reinterpret_cast<const uint2*>(&mw[3*NPTS+n]);
      a0 = fmaf(fv.x,uplo(m0.x),a0); a0 = fmaf(fv.y,uphi(m0.x),a0);
      a0 = fmaf(fv.z,uplo(m0.y),a0); a0 = fmaf(fv.w,uphi(m0.y),a0);
      a1 = fmaf(fv.x,uplo(m1.x),a1); a1 = fmaf(fv.y,uphi(m1.x),a1);
      a1 = fmaf(fv.z,uplo(m1.y),a1); a1 = fmaf(fv.w,uphi(m1.y),a1);
      a2 = fmaf(fv.x,uplo(m2.x),a2); a2 = fmaf(fv.y,uphi(m2.x),a2);
      a2 = fmaf(fv.z,uplo(m2.y),a2); a2 = fmaf(fv.w,uphi(m2.y),a2);
      a3 = fmaf(fv.x,uplo(m3.x),a3); a3 = fmaf(fv.y,uphi(m3.x),a3);
      a3 = fmaf(fv.z,uplo(m3.y),a3); a3 = fmaf(fv.w,uphi(m3.y),a3);
    }
  }
#pragma unroll
  for (int o=1;o<16;o<<=1){
    a0 += __shfl_xor(a0,o); a1 += __shfl_xor(a1,o);
    a2 += __shfl_xor(a2,o); a3 += __shfl_xor(a3,o);
  }
  if (ln == 0){
    atomicAdd(&pool_acc[(b*4+0)*CD + c], a0);
    atomicAdd(&pool_acc[(b*4+1)*CD + c], a1);
    atomicAdd(&pool_acc[(b*4+2)*CD + c], a2);
    atomicAdd(&pool_acc[(b*4+3)*CD + c], a3);
  }
}

__global__ __launch_bounds__(256)
void k_final(const float* __restrict__ pool_acc, const float* __restrict__ denom,
             const float* __restrict__ globalv, float* __restrict__ out)
{
  int t = blockIdx.x*256 + threadIdx.x;   // 2048
  int bv = t>>7, c = t&127, b = bv>>2;
  out[t] = pool_acc[t]/(denom[bv]+1e-8f) + globalv[b*CD+c];
}

extern "C" void kernel_launch(void* const* d_in, const int* in_sizes, int n_in,
                              void* d_out, int out_size, void* d_ws,
                              size_t ws_size, hipStream_t stream) {
  const float* xyz  = (const float*)d_in[0];
  const float* feat = (const float*)d_in[1];
  const float* masks= (const float*)d_in[2];
  const float* W1 = (const float*)d_in[3];
  const float* b1 = (const float*)d_in[4];
  const float* g1 = (const float*)d_in[5];
  const float* be1= (const float*)d_in[6];
  const float* W2 = (const float*)d_in[7];
  const float* b2 = (const float*)d_in[8];
  const float* g2 = (const float*)d_in[9];
  const float* be2= (const float*)d_in[10];
  const float* W3 = (const float*)d_in[11];
  const float* b3 = (const float*)d_in[12];
  const float* g3 = (const float*)d_in[13];
  const float* be3= (const float*)d_in[14];
  const float* W4 = (const float*)d_in[15];
  float* out = (float*)d_out;

  char* ws = (char*)d_ws;
  unsigned* kmax    = (unsigned*)ws;                   // 2048 B
  unsigned* kmin    = (unsigned*)(ws + 2048);          // 2048 B
  float*    denom   = (float*)(ws + 4096);             // 64 B
  float*    pool_acc= (float*)(ws + 4352);             // 8192 B
  float*    globalv = (float*)(ws + 12544);            // 2048 B
  float*    gcomb   = (float*)(ws + 14592);            // 2048 B
  unsigned short* mwT = (unsigned short*)(ws + 16640); // 1.28 MB
  unsigned* z2u     = (unsigned*)(ws + 5136640);       // 40.96 MB

  k_init<<<16, 256, 0, stream>>>(kmax, kmin, denom, pool_acc);
  k_A<<<1280, 256, 0, stream>>>(xyz, W1, b1, g1, be1, W2, b2, z2u, kmax, kmin);
  k_global<<<4, 256, 0, stream>>>(kmax, kmin, g2, be2, W3, b3, globalv, gcomb);
  k_B<<<1280, 256, 0, stream>>>(z2u, g2, W3, g3, be3, W4, masks, gcomb, mwT, denom);
  k_pool<<<512, 256, 0, stream>>>(feat, mwT, pool_acc);
  k_final<<<8, 256, 0, stream>>>(pool_acc, denom, globalv, out);
}

// Round 7
// 148.808 us; speedup vs baseline: 2.1439x; 2.1439x over previous
//
#include <hip/hip_runtime.h>
#include <stdint.h>

// GeoAwarePooling B=4, N=40000, C=128, V=4.
// xyz is broadcast across views -> per-point MLP runs once over B*N points.
// v7: anti-spill. K=32 MFMA, W fragments in LDS [frag][lane] (conflict-free
// b128), wave-private XOR-swizzled transpose tile, z2 stored in B-frag layout
// (phase B loop is LDS-free), minimal live registers, small loop bodies.

#define NPTS 40000
#define CD   128

typedef __attribute__((ext_vector_type(8))) short bf8_t;
typedef __attribute__((ext_vector_type(4))) float f4_t;

__device__ __forceinline__ unsigned short f2bfu(float f){
  unsigned u = __float_as_uint(f);
  u += 0x7FFFu + ((u>>16)&1u);               // RNE
  return (unsigned short)(u>>16);
}
__device__ __forceinline__ float bfhi_f(float f){   // f rounded to bf16, as f32
  return __uint_as_float(((unsigned)f2bfu(f))<<16);
}
__device__ __forceinline__ unsigned pk2(float a, float b){
  return (unsigned)f2bfu(a) | ((unsigned)f2bfu(b)<<16);
}
__device__ __forceinline__ float uplo(unsigned u){ return __uint_as_float(u<<16); }
__device__ __forceinline__ float uphi(unsigned u){ return __uint_as_float(u & 0xFFFF0000u); }
__device__ __forceinline__ unsigned fenc(float f){  // order-preserving key
  unsigned u = __float_as_uint(f);
  return (u & 0x80000000u) ? ~u : (u | 0x80000000u);
}
__device__ __forceinline__ float fdec(unsigned k){
  return (k & 0x80000000u) ? __uint_as_float(k & 0x7FFFFFFFu) : __uint_as_float(~k);
}
__device__ __forceinline__ bf8_t bc8(uint4 v){ return __builtin_bit_cast(bf8_t, v); }

__global__ __launch_bounds__(256)
void k_init(unsigned* __restrict__ kmax, unsigned* __restrict__ kmin,
            float* __restrict__ denom, float* __restrict__ pool_acc){
  int t = blockIdx.x*256 + threadIdx.x;
  if (t < 512){ kmax[t] = 0u; kmin[t] = 0xFFFFFFFFu; }
  if (t < 16) denom[t] = 0.f;
  if (t < 2048) pool_acc[t] = 0.f;
}

// ---------------------------------------------------------------------------
// Phase A: y=xyz@W1+b1 (K=32 MFMA, hi/lo split, fp32-exact); h=relu(LN1(y));
// z=(h@W2+b2 normalized, pre-affine) -> global in B-FRAGMENT layout:
// z2g[(it*4+ks)*64+lane] = uint4 frag (channels 32ks+8g..+7 of point m).
// 8 waves/block share the W2 fragment tile; 1 tile(16 pts)/wave-iteration.
// ---------------------------------------------------------------------------
__global__ __launch_bounds__(512)
void k_A(const float* __restrict__ xyz,
         const float* __restrict__ W1, const float* __restrict__ b1,
         const float* __restrict__ g1, const float* __restrict__ be1,
         const float* __restrict__ W2, const float* __restrict__ b2,
         uint4* __restrict__ z2g)
{
  __shared__ uint4 W2F[2048];        // 32 KiB  [frag=ks*8+mto][lane]
  __shared__ uint4 A1F[512];         // 8 KiB   [mto][lane]
  __shared__ uint4 Hb4[8][16][16];   // 32 KiB  per-wave transpose tile
  __shared__ uint2 P1u[32], P2u[32], P3u[32];

  const int tid = threadIdx.x;
  for (int e = tid; e < 2048; e += 512){
    int f = e >> 6, l = e & 63;
    int ks = f >> 3, mto = f & 7;
    int lm = l & 15, lg = l >> 4;
    int ci = 32*ks + 8*lg, co = 16*mto + lm;
    uint4 v;
    v.x = pk2(W2[(ci+0)*CD+co], W2[(ci+1)*CD+co]);
    v.y = pk2(W2[(ci+2)*CD+co], W2[(ci+3)*CD+co]);
    v.z = pk2(W2[(ci+4)*CD+co], W2[(ci+5)*CD+co]);
    v.w = pk2(W2[(ci+6)*CD+co], W2[(ci+7)*CD+co]);
    W2F[e] = v;
  }
  {
    int mto = tid >> 6, l = tid & 63;
    int lm = l & 15, lg = l >> 4;
    int c = 16*mto + lm;
    float w0=W1[c], w1=W1[CD+c], w2=W1[2*CD+c], bb=b1[c];
    uint4 v = {0u,0u,0u,0u};
    if (lg==0){ v.x=pk2(w0,w1); v.y=pk2(w2,w0); v.z=pk2(w1,w2);
                v.w=pk2(w0-bfhi_f(w0), w1-bfhi_f(w1)); }
    else if (lg==1){ v.x=pk2(w2-bfhi_f(w2), bb); v.y=pk2(bb-bfhi_f(bb),0.f); }
    A1F[tid] = v;
  }
  if (tid < 32){
    int t4 = tid*4;
    uint2 v;
    v.x = pk2(g1[t4], g1[t4+1]);  v.y = pk2(g1[t4+2], g1[t4+3]);  P1u[tid] = v;
    v.x = pk2(be1[t4],be1[t4+1]); v.y = pk2(be1[t4+2],be1[t4+3]); P2u[tid] = v;
    v.x = pk2(b2[t4], b2[t4+1]);  v.y = pk2(b2[t4+2], b2[t4+3]);  P3u[tid] = v;
  }
  __syncthreads();

  const int wave = tid>>6, lane = tid&63;
  const int m = lane&15, g = lane>>4;
  const int b  = blockIdx.x / 80;              // 80 blocks per batch
  const int wb = (blockIdx.x % 80)*8 + wave;   // 0..639 within batch
  const int swz = m & 7;
  const float* xyzb = xyz + (size_t)3*b*NPTS;
  uint2* Hb2 = (uint2*)&Hb4[wave][0][0];

#pragma unroll 1
  for (int rep = 0; rep < 4; ++rep){
    const int tb = wb + rep*640;
    if (tb >= 2500) break;
    const int it = b*2500 + tb;
    const int n = tb*16 + m;
    float px = xyzb[n], py = xyzb[NPTS+n], pz = xyzb[2*NPTS+n];

    uint4 B1u = {0u,0u,0u,0u};
    if (g==0){ B1u.x = pk2(px,py); B1u.y = pk2(pz, px-bfhi_f(px));
               B1u.z = pk2(py-bfhi_f(py), pz-bfhi_f(pz)); B1u.w = pk2(px,py); }
    else if (g==1){ B1u.x = pk2(pz, 1.0f); B1u.y = pk2(1.0f, 0.f); }
    bf8_t B1 = bc8(B1u);

    // GEMM1
    f4_t acc[8];
#pragma unroll
    for (int mt=0;mt<8;++mt)
      acc[mt] = __builtin_amdgcn_mfma_f32_16x16x32_bf16(
                    bc8(A1F[mt*64+lane]), B1, (f4_t){0.f,0.f,0.f,0.f}, 0,0,0);

    // LN1
    float s1=0.f, s2=0.f;
#pragma unroll
    for (int mt=0;mt<8;++mt)
#pragma unroll
      for (int r=0;r<4;++r){ float v=acc[mt][r]; s1+=v; s2=fmaf(v,v,s2); }
    s1 += __shfl_xor(s1,16); s1 += __shfl_xor(s1,32);
    s2 += __shfl_xor(s2,16); s2 += __shfl_xor(s2,32);
    float mu = s1*(1.f/128.f);
    float rs = rsqrtf(fmaxf(s2*(1.f/128.f)-mu*mu,0.f)+1e-5f);

    // affine+relu -> write h pairs into swizzled transpose tile
#pragma unroll
    for (int mt=0;mt<8;++mt){
      uint2 gv = P1u[4*mt+g], bv = P2u[4*mt+g];
      float h0 = fmaxf(0.f, fmaf((acc[mt][0]-mu)*rs, uplo(gv.x), uplo(bv.x)));
      float h1 = fmaxf(0.f, fmaf((acc[mt][1]-mu)*rs, uphi(gv.x), uphi(bv.x)));
      float h2 = fmaxf(0.f, fmaf((acc[mt][2]-mu)*rs, uplo(gv.y), uplo(bv.y)));
      float h3 = fmaxf(0.f, fmaf((acc[mt][3]-mu)*rs, uphi(gv.y), uphi(bv.y)));
      uint2 wv; wv.x = pk2(h0,h1); wv.y = pk2(h2,h3);
      int slot = ((mt>>1)*4 + 2*(mt&1) + (g>>1)) ^ swz;
      Hb2[(m*16 + slot)*2 + (g&1)] = wv;
    }

    // GEMM2: B-frags from transpose tile, A-frags from W2F
    f4_t a2[8];
#pragma unroll
    for (int mt=0;mt<8;++mt) a2[mt]=(f4_t){0.f,0.f,0.f,0.f};
#pragma unroll
    for (int ks=0;ks<4;++ks){
      bf8_t Bf = bc8(Hb4[wave][m][(ks*4+g)^swz]);
#pragma unroll
      for (int mto=0;mto<8;++mto)
        a2[mto] = __builtin_amdgcn_mfma_f32_16x16x32_bf16(
                      bc8(W2F[(ks*8+mto)*64+lane]), Bf, a2[mto], 0,0,0);
    }

    // +b2, LN2
    s1=0.f; s2=0.f;
#pragma unroll
    for (int mt=0;mt<8;++mt){
      uint2 bv = P3u[4*mt+g];
      a2[mt][0]+=uplo(bv.x); a2[mt][1]+=uphi(bv.x);
      a2[mt][2]+=uplo(bv.y); a2[mt][3]+=uphi(bv.y);
#pragma unroll
      for (int r=0;r<4;++r){ float v=a2[mt][r]; s1+=v; s2=fmaf(v,v,s2); }
    }
    s1 += __shfl_xor(s1,16); s1 += __shfl_xor(s1,32);
    s2 += __shfl_xor(s2,16); s2 += __shfl_xor(s2,32);
    mu = s1*(1.f/128.f);
    rs = rsqrtf(fmaxf(s2*(1.f/128.f)-mu*mu,0.f)+1e-5f);

    // z pairs -> transpose tile -> read frags -> coalesced global store
#pragma unroll
    for (int mt=0;mt<8;++mt){
      float z0=(a2[mt][0]-mu)*rs, z1=(a2[mt][1]-mu)*rs;
      float z2v=(a2[mt][2]-mu)*rs, z3=(a2[mt][3]-mu)*rs;
      uint2 wv; wv.x=pk2(z0,z1); wv.y=pk2(z2v,z3);
      int slot = ((mt>>1)*4 + 2*(mt&1) + (g>>1)) ^ swz;
      Hb2[(m*16 + slot)*2 + (g&1)] = wv;
    }
#pragma unroll
    for (int ks=0;ks<4;++ks){
      uint4 frag = Hb4[wave][m][(ks*4+g)^swz];
      z2g[(size_t)(it*4+ks)*64 + lane] = frag;
    }
  }
}

// per-channel max/min scan of z2 (frag layout). wave w handles k-slice w.
__global__ __launch_bounds__(256)
void k_cmax(const uint4* __restrict__ z2g, unsigned* __restrict__ kmax,
            unsigned* __restrict__ kmin)
{
  const int wave = threadIdx.x>>6, lane = threadIdx.x&63;
  const int m = lane&15, g = lane>>4;
  const int blk = blockIdx.x;            // 500 blocks; 125/batch (20 tiles each)
  const int b = blk/125;
  const int ks = wave;
  float mx[8], mn[8];
#pragma unroll
  for (int j=0;j<8;++j){ mx[j]=-1e30f; mn[j]=1e30f; }
#pragma unroll 1
  for (int t=0;t<20;++t){
    int it = blk*20 + t;
    uint4 v = z2g[(size_t)(it*4+ks)*64 + lane];
    unsigned u0=v.x,u1=v.y,u2=v.z,u3=v.w;
    mx[0]=fmaxf(mx[0],uplo(u0)); mn[0]=fminf(mn[0],uplo(u0));
    mx[1]=fmaxf(mx[1],uphi(u0)); mn[1]=fminf(mn[1],uphi(u0));
    mx[2]=fmaxf(mx[2],uplo(u1)); mn[2]=fminf(mn[2],uplo(u1));
    mx[3]=fmaxf(mx[3],uphi(u1)); mn[3]=fminf(mn[3],uphi(u1));
    mx[4]=fmaxf(mx[4],uplo(u2)); mn[4]=fminf(mn[4],uplo(u2));
    mx[5]=fmaxf(mx[5],uphi(u2)); mn[5]=fminf(mn[5],uphi(u2));
    mx[6]=fmaxf(mx[6],uplo(u3)); mn[6]=fminf(mn[6],uplo(u3));
    mx[7]=fmaxf(mx[7],uphi(u3)); mn[7]=fminf(mn[7],uphi(u3));
  }
#pragma unroll
  for (int j=0;j<8;++j){
#pragma unroll
    for (int o=1;o<16;o<<=1){
      mx[j]=fmaxf(mx[j],__shfl_xor(mx[j],o));
      mn[j]=fminf(mn[j],__shfl_xor(mn[j],o));
    }
  }
  if (m==0){
#pragma unroll
    for (int j=0;j<8;++j){
      int c = 32*ks + 8*g + j;
      atomicMax(&kmax[b*CD+c], fenc(mx[j]));
      atomicMin(&kmin[b*CD+c], fenc(mn[j]));
    }
  }
}

// global[b][c] = g2*(g2>=0?zmax:zmin)+be2 ; gcomb = b3 + be2@W3top + global@W3bot
__global__ __launch_bounds__(256)
void k_global(const unsigned* __restrict__ kmax, const unsigned* __restrict__ kmin,
              const float* __restrict__ g2, const float* __restrict__ be2,
              const float* __restrict__ W3, const float* __restrict__ b3,
              float* __restrict__ globalv, float* __restrict__ gcomb)
{
  __shared__ float gs[128], bs[128], part[256];
  int b = blockIdx.x;
  int t = threadIdx.x;
  if (t < 128){
    float gg = g2[t];
    float zx = fdec(kmax[b*CD+t]), zn = fdec(kmin[b*CD+t]);
    float gl = (gg>=0.f ? gg*zx : gg*zn) + be2[t];
    gs[t] = gl;
    globalv[b*CD+t] = gl;
    bs[t] = be2[t];
  }
  __syncthreads();
  int c = t & 127, half = t >> 7;
  float accv = 0.f;
  if (half==0){
    for (int k=0;k<128;++k) accv = fmaf(bs[k], W3[k*CD+c], accv);
    accv += b3[c];
  } else {
    for (int k=0;k<128;++k) accv = fmaf(gs[k], W3[(128+k)*CD+c], accv);
  }
  part[t] = accv;
  __syncthreads();
  if (half==0) gcomb[b*CD+c] = part[c] + part[128+c];
}

// ---------------------------------------------------------------------------
// Phase B: u = z2@(g2*W3top) + gcomb; h2=relu(LN3(u)); w=2*sigmoid(h2@W4).
// z2 loaded directly as B-frags from global; loop body has zero LDS traffic
// except broadcast param reads.
// ---------------------------------------------------------------------------
__global__ __launch_bounds__(512)
void k_B(const uint4* __restrict__ z2g, const float* __restrict__ g2,
         const float* __restrict__ W3, const float* __restrict__ g3,
         const float* __restrict__ be3, const float* __restrict__ W4,
         const float* __restrict__ masks, const float* __restrict__ gcomb,
         unsigned short* __restrict__ mwT, float* __restrict__ denom)
{
  __shared__ uint4 W3F[2048];        // g2 folded into rows
  __shared__ uint2 Pg[32], Pb[32], Pw[32];
  __shared__ float GC[128];

  const int tid = threadIdx.x;
  const int b = blockIdx.x / 80;
  for (int e = tid; e < 2048; e += 512){
    int f = e >> 6, l = e & 63;
    int ks = f >> 3, mto = f & 7;
    int lm = l & 15, lg = l >> 4;
    int ci = 32*ks + 8*lg, co = 16*mto + lm;
    uint4 v;
    v.x = pk2(g2[ci+0]*W3[(ci+0)*CD+co], g2[ci+1]*W3[(ci+1)*CD+co]);
    v.y = pk2(g2[ci+2]*W3[(ci+2)*CD+co], g2[ci+3]*W3[(ci+3)*CD+co]);
    v.z = pk2(g2[ci+4]*W3[(ci+4)*CD+co], g2[ci+5]*W3[(ci+5)*CD+co]);
    v.w = pk2(g2[ci+6]*W3[(ci+6)*CD+co], g2[ci+7]*W3[(ci+7)*CD+co]);
    W3F[e] = v;
  }
  if (tid < 32){
    int t4 = tid*4;
    uint2 v;
    v.x = pk2(g3[t4], g3[t4+1]);  v.y = pk2(g3[t4+2], g3[t4+3]);  Pg[tid] = v;
    v.x = pk2(be3[t4],be3[t4+1]); v.y = pk2(be3[t4+2],be3[t4+3]); Pb[tid] = v;
    v.x = pk2(W4[t4], W4[t4+1]);  v.y = pk2(W4[t4+2], W4[t4+3]);  Pw[tid] = v;
  }
  if (tid < 128) GC[tid] = gcomb[b*CD + tid];
  __syncthreads();

  const int wave = tid>>6, lane = tid&63;
  const int m = lane&15, g = lane>>4;
  const int wb = (blockIdx.x % 80)*8 + wave;
  float dacc = 0.f;

#pragma unroll 1
  for (int rep = 0; rep < 4; ++rep){
    const int tb = wb + rep*640;
    if (tb >= 2500) break;
    const int it = b*2500 + tb;
    const int n = tb*16 + m;

    uint4 zf0 = z2g[(size_t)(it*4+0)*64 + lane];
    uint4 zf1 = z2g[(size_t)(it*4+1)*64 + lane];
    uint4 zf2 = z2g[(size_t)(it*4+2)*64 + lane];
    uint4 zf3 = z2g[(size_t)(it*4+3)*64 + lane];

    f4_t a3[8];
#pragma unroll
    for (int mt=0;mt<8;++mt) a3[mt]=(f4_t){0.f,0.f,0.f,0.f};
#pragma unroll
    for (int ks=0;ks<4;++ks){
      bf8_t Bf = bc8(ks==0 ? zf0 : ks==1 ? zf1 : ks==2 ? zf2 : zf3);
#pragma unroll
      for (int mto=0;mto<8;++mto)
        a3[mto] = __builtin_amdgcn_mfma_f32_16x16x32_bf16(
                      bc8(W3F[(ks*8+mto)*64+lane]), Bf, a3[mto], 0,0,0);
    }

    float s1=0.f, s2=0.f;
#pragma unroll
    for (int mt=0;mt<8;++mt){
      float4 gcq = *reinterpret_cast<const float4*>(&GC[16*mt+4*g]);
      a3[mt][0]+=gcq.x; a3[mt][1]+=gcq.y; a3[mt][2]+=gcq.z; a3[mt][3]+=gcq.w;
#pragma unroll
      for (int r=0;r<4;++r){ float v=a3[mt][r]; s1+=v; s2=fmaf(v,v,s2); }
    }
    s1 += __shfl_xor(s1,16); s1 += __shfl_xor(s1,32);
    s2 += __shfl_xor(s2,16); s2 += __shfl_xor(s2,32);
    float mu = s1*(1.f/128.f);
    float rs = rsqrtf(fmaxf(s2*(1.f/128.f)-mu*mu,0.f)+1e-5f);

    float U = 0.f;
#pragma unroll
    for (int mt=0;mt<8;++mt){
      uint2 gv = Pg[4*mt+g], bv = Pb[4*mt+g], wv = Pw[4*mt+g];
      float h0 = fmaxf(0.f, fmaf((a3[mt][0]-mu)*rs, uplo(gv.x), uplo(bv.x)));
      float h1 = fmaxf(0.f, fmaf((a3[mt][1]-mu)*rs, uphi(gv.x), uphi(bv.x)));
      float h2 = fmaxf(0.f, fmaf((a3[mt][2]-mu)*rs, uplo(gv.y), uplo(bv.y)));
      float h3 = fmaxf(0.f, fmaf((a3[mt][3]-mu)*rs, uphi(gv.y), uphi(bv.y)));
      U = fmaf(h0, uplo(wv.x), U); U = fmaf(h1, uphi(wv.x), U);
      U = fmaf(h2, uplo(wv.y), U); U = fmaf(h3, uphi(wv.y), U);
    }
    U += __shfl_xor(U,16); U += __shfl_xor(U,32);
    float w = 2.f/(1.f + __expf(-U));
    float msk = masks[(size_t)(4*b+g)*NPTS + n];
    mwT[(size_t)(b*4+g)*NPTS + n] = f2bfu(msk*w);
    dacc += msk*w;
  }

  dacc += __shfl_xor(dacc,1); dacc += __shfl_xor(dacc,2);
  dacc += __shfl_xor(dacc,4); dacc += __shfl_xor(dacc,8);
  if (m==0) atomicAdd(&denom[b*4+g], dacc);
}

// pooled[b,v,c] = sum_n mw[b,v,n]*feat[b,c,n]  — coalesced VALU reduction.
__global__ __launch_bounds__(256)
void k_pool(const float* __restrict__ feat, const unsigned short* __restrict__ mwT,
            float* __restrict__ pool_acc)
{
  const int b   = blockIdx.x >> 7;
  const int cg  = (blockIdx.x >> 4) & 7;
  const int nch = blockIdx.x & 15;
  const int cl  = threadIdx.x >> 4, ln = threadIdx.x & 15;
  const int c   = cg*16 + cl;
  const int ns  = nch*2500;
  const float* f = &feat[((size_t)b*CD + c)*NPTS];
  const unsigned short* mw = &mwT[(size_t)b*4*NPTS];
  float a0=0.f, a1=0.f, a2=0.f, a3=0.f;
#pragma unroll 2
  for (int itr=0; itr<40; ++itr){
    int n = ns + itr*64 + ln*4;
    if (n < ns + 2500){
      float4 fv = *reinterpret_cast<const float4*>(&f[n]);
      uint2 m0 = *reinterpret_cast<const uint2*>(&mw[0*NPTS+n]);
      uint2 m1 = *reinterpret_cast<const uint2*>(&mw[1*NPTS+n]);
      uint2 m2 = *reinterpret_cast<const uint2*>(&mw[2*NPTS+n]);
      uint2 m3 = *reinterpret_cast<const uint2*>(&mw[3*NPTS+n]);
      a0 = fmaf(fv.x,uplo(m0.x),a0); a0 = fmaf(fv.y,uphi(m0.x),a0);
      a0 = fmaf(fv.z,uplo(m0.y),a0); a0 = fmaf(fv.w,uphi(m0.y),a0);
      a1 = fmaf(fv.x,uplo(m1.x),a1); a1 = fmaf(fv.y,uphi(m1.x),a1);
      a1 = fmaf(fv.z,uplo(m1.y),a1); a1 = fmaf(fv.w,uphi(m1.y),a1);
      a2 = fmaf(fv.x,uplo(m2.x),a2); a2 = fmaf(fv.y,uphi(m2.x),a2);
      a2 = fmaf(fv.z,uplo(m2.y),a2); a2 = fmaf(fv.w,uphi(m2.y),a2);
      a3 = fmaf(fv.x,uplo(m3.x),a3); a3 = fmaf(fv.y,uphi(m3.x),a3);
      a3 = fmaf(fv.z,uplo(m3.y),a3); a3 = fmaf(fv.w,uphi(m3.y),a3);
    }
  }
#pragma unroll
  for (int o=1;o<16;o<<=1){
    a0 += __shfl_xor(a0,o); a1 += __shfl_xor(a1,o);
    a2 += __shfl_xor(a2,o); a3 += __shfl_xor(a3,o);
  }
  if (ln == 0){
    atomicAdd(&pool_acc[(b*4+0)*CD + c], a0);
    atomicAdd(&pool_acc[(b*4+1)*CD + c], a1);
    atomicAdd(&pool_acc[(b*4+2)*CD + c], a2);
    atomicAdd(&pool_acc[(b*4+3)*CD + c], a3);
  }
}

__global__ __launch_bounds__(256)
void k_final(const float* __restrict__ pool_acc, const float* __restrict__ denom,
             const float* __restrict__ globalv, float* __restrict__ out)
{
  int t = blockIdx.x*256 + threadIdx.x;   // 2048
  int bv = t>>7, c = t&127, b = bv>>2;
  out[t] = pool_acc[t]/(denom[bv]+1e-8f) + globalv[b*CD+c];
}

extern "C" void kernel_launch(void* const* d_in, const int* in_sizes, int n_in,
                              void* d_out, int out_size, void* d_ws,
                              size_t ws_size, hipStream_t stream) {
  const float* xyz  = (const float*)d_in[0];
  const float* feat = (const float*)d_in[1];
  const float* masks= (const float*)d_in[2];
  const float* W1 = (const float*)d_in[3];
  const float* b1 = (const float*)d_in[4];
  const float* g1 = (const float*)d_in[5];
  const float* be1= (const float*)d_in[6];
  const float* W2 = (const float*)d_in[7];
  const float* b2 = (const float*)d_in[8];
  const float* g2 = (const float*)d_in[9];
  const float* be2= (const float*)d_in[10];
  const float* W3 = (const float*)d_in[11];
  const float* b3 = (const float*)d_in[12];
  const float* g3 = (const float*)d_in[13];
  const float* be3= (const float*)d_in[14];
  const float* W4 = (const float*)d_in[15];
  float* out = (float*)d_out;

  char* ws = (char*)d_ws;
  unsigned* kmax    = (unsigned*)ws;                   // 2048 B
  unsigned* kmin    = (unsigned*)(ws + 2048);          // 2048 B
  float*    denom   = (float*)(ws + 4096);             // 64 B
  float*    pool_acc= (float*)(ws + 4352);             // 8192 B
  float*    globalv = (float*)(ws + 12544);            // 2048 B
  float*    gcomb   = (float*)(ws + 14592);            // 2048 B
  unsigned short* mwT = (unsigned short*)(ws + 16640); // 1.28 MB
  uint4*    z2g     = (uint4*)(ws + 5136640);          // 40.96 MB

  k_init<<<16, 256, 0, stream>>>(kmax, kmin, denom, pool_acc);
  k_A<<<320, 512, 0, stream>>>(xyz, W1, b1, g1, be1, W2, b2, z2g);
  k_cmax<<<500, 256, 0, stream>>>(z2g, kmax, kmin);
  k_global<<<4, 256, 0, stream>>>(kmax, kmin, g2, be2, W3, b3, globalv, gcomb);
  k_B<<<320, 512, 0, stream>>>(z2g, g2, W3, g3, be3, W4, masks, gcomb, mwT, denom);
  k_pool<<<512, 256, 0, stream>>>(feat, mwT, pool_acc);
  k_final<<<8, 256, 0, stream>>>(pool_acc, denom, globalv, out);
}